// Round 9
// baseline (167.883 us; speedup 1.0000x reference)
//
#include <hip/hip_runtime.h>
#include <cmath>

#define TW 32
#define SUB 32            // output rows per sub-tile
#define HR (SUB + 10)     // 42-row window per buffer
#define BOFF (HR * TW)    // float4 offset of buffer B
#define NT 256
#define IMG 512
#define SSIM_C1 1e-4f
#define SSIM_C2 9e-4f

struct GaussWin { float g[11]; };

typedef float v2f __attribute__((ext_vector_type(2)));

// Native packed fp32: clang/LLVM selects v_pk_fma_f32 for <2 x float> on
// gfx90a+ (HasPackedFP32Ops).
__device__ __forceinline__ v2f pk_fma(v2f a, v2f b, v2f c) {
    return __builtin_elementwise_fma(a, b, c);
}

// R9: double-buffered LDS + pre-issued loads = in-block latency hiding.
// Session model: dur = work_equiv / busy. Work is down to ~36.6 us-equiv
// (R8) but busy never exceeded 76% because phase-1 global-load latency is
// exposed against the barrier. R6/R7 failed because sub-tile loads sat in
// an interval whose other work DEPENDED on them. Here: window-1's 12
// float4 loads are issued into registers at the start of the interval that
// runs ph2(0) on buffer A (independent FMA work, ~300+ cycles), and are
// consumed by h_compute(1) into buffer B at the end of the same interval.
// The vmcnt(0)-before-barrier drain is harmless: loads are done by then.
// LDS 43 KB -> 3 blocks/CU (bet: in-block overlap replaces block churn).
// launch_bounds(256,3) -> VGPR cap 170, no spill (R4 lesson; tripwire:
// WRITE_SIZE must stay ~0.2 MB).

__device__ __forceinline__ void h_load(const float* __restrict__ xp,
                                       const float* __restrict__ yp,
                                       int tx0, int gy0, int nrows, int tid,
                                       float4 fx[6], float4 fy[6]) {
    if (tid < nrows * 4) {
        const int r = tid >> 2;
        const int cs = (tid & 3) * 8;
        const int gy = gy0 + r;
        const float* xrow = xp + gy * IMG;
        const float* yrow = yp + gy * IMG;
        const int c0 = tx0 + cs - 8;
        // Per-strip fast path: row in-bounds AND col window [c0,c0+24) in-image.
        const bool fast = ((unsigned)gy < IMG) & ((unsigned)c0 <= (unsigned)(IMG - 24));
        if (fast) {
            #pragma unroll
            for (int q = 0; q < 6; q++) {
                fx[q] = *(const float4*)(xrow + c0 + 4 * q);
                fy[q] = *(const float4*)(yrow + c0 + 4 * q);
            }
        } else {
            const bool rowok = ((unsigned)gy < IMG);
            #pragma unroll
            for (int q = 0; q < 6; q++) {
                int col = c0 + 4 * q;
                fx[q] = make_float4(0.f, 0.f, 0.f, 0.f);
                fy[q] = make_float4(0.f, 0.f, 0.f, 0.f);
                if (rowok && (unsigned)col <= (unsigned)(IMG - 4)) {
                    fx[q] = *(const float4*)(xrow + col);
                    fy[q] = *(const float4*)(yrow + col);
                }
            }
        }
    }
}

__device__ __forceinline__ void h_compute(int slot0, int nrows, int tid,
                                          const v2f* __restrict__ w2,
                                          const float4 fx[6], const float4 fy[6],
                                          float4* __restrict__ buf) {
    constexpr int WI[11] = {0,1,2,3,4,5,4,3,2,1,0};
    if (tid < nrows * 4) {
        const int r = tid >> 2;
        const int cs = (tid & 3) * 8;
        const int slot = slot0 + r;
        float vxa[24], vya[24];
        #pragma unroll
        for (int q = 0; q < 6; q++) {
            vxa[4*q+0]=fx[q].x; vxa[4*q+1]=fx[q].y; vxa[4*q+2]=fx[q].z; vxa[4*q+3]=fx[q].w;
            vya[4*q+0]=fy[q].x; vya[4*q+1]=fy[q].y; vya[4*q+2]=fy[q].z; vya[4*q+3]=fy[q].w;
        }
        // Streaming tap-major conv over the two packed accumulators
        // (four-field: A=(x,y), B=(x^2+y^2, x*y)).
        v2f amu[8], a2[8];
        #pragma unroll
        for (int j = 0; j < 8; j++) { amu[j]=(v2f){0.f,0.f}; a2[j]=(v2f){0.f,0.f}; }
        #pragma unroll
        for (int k = 0; k < 18; k++) {
            float xv = vxa[k + 3], yv = vya[k + 3];
            v2f xy = (v2f){xv, yv};
            v2f p2 = xy * xy;
            v2f zw = (v2f){p2.x + p2.y, xv * yv};
            const int jlo = (k - 10 > 0) ? (k - 10) : 0;
            const int jhi = (k < 7) ? k : 7;
            #pragma unroll
            for (int j = jlo; j <= jhi; j++) {
                v2f w = w2[WI[k - j]];
                amu[j] = pk_fma(xy, w, amu[j]);
                a2[j]  = pk_fma(zw, w, a2[j]);
            }
        }
        const int quad = cs & 24;
        const int base0 = cs + 2 * (cs >> 3) + 5 * slot;
        #pragma unroll
        for (int j = 0; j < 8; j++) {
            int pc = quad | ((base0 + j) & 7);
            buf[slot * TW + pc] = make_float4(amu[j].x, amu[j].y, a2[j].x, a2[j].y);
        }
    }
}

__launch_bounds__(NT, 3)
__global__ void ssim_tile_kernel(const float* __restrict__ x,
                                 const float* __restrict__ y,
                                 const float* __restrict__ conf,
                                 float* __restrict__ partials,
                                 float* __restrict__ out,
                                 int use_ws, float scale,
                                 GaussWin W) {
    __shared__ float4 s_h[2 * HR * TW];   // 43008 B: buffers A and B
    __shared__ float  s_red[4];           // 3 blocks/CU

    const int tid = threadIdx.x;
    const int plane = blockIdx.z;              // b*3 + c
    const int tx0 = blockIdx.x * TW;
    const int ty0 = blockIdx.y * (2 * SUB);
    const float* xp = x + plane * (IMG * IMG);
    const float* yp = y + plane * (IMG * IMG);
    const int cbase = (plane / 3) * (IMG * IMG);

    // Gaussian symmetric: 6 distinct packed weights.
    constexpr int WI[11] = {0,1,2,3,4,5,4,3,2,1,0};
    v2f w2[6];
    #pragma unroll
    for (int i = 0; i < 6; i++) w2[i] = (v2f){W.g[i], W.g[i]};

    // Phase-2 addressing (identical for both sub-tiles / both buffers):
    // swizzled col has period 8 in t (5*8 == 0 mod 8) -> 8 precomputed
    // bases; t*TW folds into the ds_read offset immediate.
    const int c   = tid & 31;
    const int r0  = (tid >> 5) * 4;           // 8 groups x 4 rows
    const int cquad = c & 24;
    const int cb0 = c + 2 * (c >> 3) + 5 * r0;
    int bidx[8];
    #pragma unroll
    for (int p = 0; p < 8; p++) {
        bidx[p] = r0 * TW + (cquad | ((cb0 + 5 * p) & 7));
    }

    float lsum = 0.f;
    float4 fx[6], fy[6];

    // ---- Window 0: rows [ty0-5, ty0+36] -> buffer A slots 0..41 ----
    h_load(xp, yp, tx0, ty0 - 5, HR, tid, fx, fy);
    float cf0[4];
    #pragma unroll
    for (int j = 0; j < 4; j++) {
        cf0[j] = conf[cbase + (ty0 + r0 + j) * IMG + tx0 + c];
    }
    h_compute(0, HR, tid, w2, fx, fy, s_h);
    __syncthreads();

    // ---- Interval 1: ph2(0) on A  ||  loads+h(1) into B ----
    // Pre-issue window-1 global loads (rows ty0+37..68 -> B slots 10..41);
    // they complete under ph2(0)'s independent FMA stream.
    h_load(xp, yp, tx0, ty0 + SUB + 5, SUB, tid, fx, fy);
    float cf1[4];
    #pragma unroll
    for (int j = 0; j < 4; j++) {
        cf1[j] = conf[cbase + (ty0 + SUB + r0 + j) * IMG + tx0 + c];
    }
    // Stash-read the 10 overlap h-rows (A slots 32..41); swizzle phases
    // align across the copy (5*32 == 0 mod 8) -> raw float4 region copy.
    float4 st0 = s_h[32 * TW + tid];
    float4 st1;
    if (tid < 64) st1 = s_h[40 * TW + tid];

    // ph2(0): vertical pass on A, 4 outputs/thread.
    {
        v2f amu[4], a2[4];
        #pragma unroll
        for (int j = 0; j < 4; j++) { amu[j]=(v2f){0.f,0.f}; a2[j]=(v2f){0.f,0.f}; }
        #pragma unroll
        for (int t = 0; t < 14; t++) {
            float4 h4 = s_h[bidx[t & 7] + t * TW];
            v2f hmu = (v2f){h4.x, h4.y};
            v2f h2  = (v2f){h4.z, h4.w};
            #pragma unroll
            for (int j = 0; j < 4; j++) {
                int k = t - j;
                if (k >= 0 && k <= 10) {
                    v2f w = w2[WI[k]];
                    amu[j] = pk_fma(hmu, w, amu[j]);
                    a2[j]  = pk_fma(h2, w, a2[j]);
                }
            }
        }
        #pragma unroll
        for (int j = 0; j < 4; j++) {
            float mu_x = amu[j].x, mu_y = amu[j].y;
            v2f prod = amu[j] * amu[j];
            float mu_xy = mu_x * mu_y;
            float musq  = prod.x + prod.y;
            float sigsum = a2[j].x - musq;
            float sigxy  = a2[j].y - mu_xy;
            float num = fmaf(2.f, mu_xy, SSIM_C1) * fmaf(2.f, sigxy, SSIM_C2);
            float den = (musq + SSIM_C1) * (sigsum + SSIM_C2);
            float ssim = num * __builtin_amdgcn_rcpf(den);
            float loss = fminf(fmaxf(1.f - ssim, 0.f), 1.f);
            lsum = fmaf(loss, cf0[j], lsum);
        }
    }

    // Stash-write B slots 0..9, then compute the 32 new h-rows -> B 10..41.
    s_h[BOFF + tid] = st0;
    if (tid < 64) s_h[BOFF + 256 + tid] = st1;
    h_compute(10, SUB, tid, w2, fx, fy, s_h + BOFF);
    __syncthreads();

    // ---- Interval 2: ph2(1) on B ----
    {
        v2f amu[4], a2[4];
        #pragma unroll
        for (int j = 0; j < 4; j++) { amu[j]=(v2f){0.f,0.f}; a2[j]=(v2f){0.f,0.f}; }
        #pragma unroll
        for (int t = 0; t < 14; t++) {
            float4 h4 = s_h[BOFF + bidx[t & 7] + t * TW];
            v2f hmu = (v2f){h4.x, h4.y};
            v2f h2  = (v2f){h4.z, h4.w};
            #pragma unroll
            for (int j = 0; j < 4; j++) {
                int k = t - j;
                if (k >= 0 && k <= 10) {
                    v2f w = w2[WI[k]];
                    amu[j] = pk_fma(hmu, w, amu[j]);
                    a2[j]  = pk_fma(h2, w, a2[j]);
                }
            }
        }
        #pragma unroll
        for (int j = 0; j < 4; j++) {
            float mu_x = amu[j].x, mu_y = amu[j].y;
            v2f prod = amu[j] * amu[j];
            float mu_xy = mu_x * mu_y;
            float musq  = prod.x + prod.y;
            float sigsum = a2[j].x - musq;
            float sigxy  = a2[j].y - mu_xy;
            float num = fmaf(2.f, mu_xy, SSIM_C1) * fmaf(2.f, sigxy, SSIM_C2);
            float den = (musq + SSIM_C1) * (sigsum + SSIM_C2);
            float ssim = num * __builtin_amdgcn_rcpf(den);
            float loss = fminf(fmaxf(1.f - ssim, 0.f), 1.f);
            lsum = fmaf(loss, cf1[j], lsum);
        }
    }

    // ---- Block reduction ----
    #pragma unroll
    for (int off = 32; off; off >>= 1) lsum += __shfl_down(lsum, off, 64);
    if ((tid & 63) == 0) s_red[tid >> 6] = lsum;
    __syncthreads();
    if (tid == 0) {
        float t = s_red[0] + s_red[1] + s_red[2] + s_red[3];
        if (use_ws) {
            partials[blockIdx.x + gridDim.x * (blockIdx.y + gridDim.y * blockIdx.z)] = t;
        } else {
            atomicAdd(out, t * scale);
        }
    }
}

// Single-block reduce: writes out[0] directly (no memset, no atomics).
__global__ void reduce_kernel(const float* __restrict__ partials, int n,
                              float* __restrict__ out, float scale) {
    __shared__ float s_red[16];
    float s = 0.f;
    const float4* p4 = (const float4*)partials;
    const int n4 = n >> 2;
    for (int i = threadIdx.x; i < n4; i += 1024) {
        float4 v = p4[i];
        s += (v.x + v.y) + (v.z + v.w);
    }
    for (int i = (n4 << 2) + threadIdx.x; i < n; i += 1024) s += partials[i];
    #pragma unroll
    for (int off = 32; off; off >>= 1) s += __shfl_down(s, off, 64);
    if ((threadIdx.x & 63) == 0) s_red[threadIdx.x >> 6] = s;
    __syncthreads();
    if (threadIdx.x == 0) {
        float t = 0.f;
        #pragma unroll
        for (int i = 0; i < 16; i++) t += s_red[i];
        out[0] = t * scale;
    }
}

extern "C" void kernel_launch(void* const* d_in, const int* in_sizes, int n_in,
                              void* d_out, int out_size, void* d_ws, size_t ws_size,
                              hipStream_t stream) {
    const float* x    = (const float*)d_in[0];
    const float* y    = (const float*)d_in[1];
    const float* conf = (const float*)d_in[2];
    float* out = (float*)d_out;
    float* partials = (float*)d_ws;

    // Gaussian window, computed like the reference: float64 exp + normalize, cast f32
    GaussWin W;
    {
        double gd[11], s = 0.0;
        for (int i = 0; i < 11; i++) { gd[i] = exp(-((i - 5) * (i - 5)) / 4.5); s += gd[i]; }
        for (int i = 0; i < 11; i++) W.g[i] = (float)(gd[i] / s);
    }

    const int B = 16, C = 3;
    const float scale = 1.0f / (float)(B * C * IMG * IMG);
    dim3 grid(IMG / TW, IMG / (2 * SUB), B * C);            // 16 x 8 x 48 = 6144 blocks
    const int nblocks = (IMG / TW) * (IMG / (2 * SUB)) * B * C;
    const int use_ws = (ws_size >= (size_t)nblocks * sizeof(float)) ? 1 : 0;

    if (!use_ws) {
        // fallback: atomic accumulation into d_out (poisoned before each call)
        hipMemsetAsync(d_out, 0, sizeof(float), stream);
    }
    ssim_tile_kernel<<<grid, NT, 0, stream>>>(x, y, conf, partials, out, use_ws, scale, W);
    if (use_ws) {
        reduce_kernel<<<1, 1024, 0, stream>>>(partials, nblocks, out, scale);
    }
}

// Round 10
// 153.931 us; speedup vs baseline: 1.0906x; 1.0906x over previous
//
#include <hip/hip_runtime.h>
#include <cmath>

#define TW 32
#define TH 40
#define HR (TH + 10)     // 50 rows of h-pass results
#define NT 256
#define IMG 512
#define SSIM_C1 1e-4f
#define SSIM_C2 9e-4f

struct GaussWin { float g[11]; };

typedef float v2f __attribute__((ext_vector_type(2)));

// Native packed fp32: clang/LLVM selects v_pk_fma_f32 for <2 x float> on
// gfx90a+ (HasPackedFP32Ops).
__device__ __forceinline__ v2f pk_fma(v2f a, v2f b, v2f c) {
    return __builtin_elementwise_fma(a, b, c);
}

// R10: TH=40 -- the interpolation point on the session's measured frontier.
//   R2 (TH=32): work 39.5 us-eq @ busy 69% (7 blk/CU) -> 57.3 us
//   R8 (TH=48): work 36.6 us-eq @ busy 62% (5 blk/CU) -> 59.0 us
// TH=40: LDS 50*32*16 = 25.6 KB -> 6 blocks/CU (R1 measured 75-76% busy at
// 6 blocks). Halo ratio 50/40 = 1.25; phase-2 reads 3.0 rows/output;
// single-round phase-1 (200 strips < 256 threads). Work ~37.5 us-eq at
// busy ~0.70 -> ~53 us. Fatter-block structures (R3/R5/R6/R7/R9) are all
// dead: busy is bought only by >=6 independent resident blocks/CU.
__launch_bounds__(NT, 4)
__global__ void ssim_tile_kernel(const float* __restrict__ x,
                                 const float* __restrict__ y,
                                 const float* __restrict__ conf,
                                 float* __restrict__ partials,
                                 float* __restrict__ out,
                                 int use_ws, float scale,
                                 GaussWin W) {
    __shared__ float4 s_h[HR * TW];     // 25600 B  (mu_x, mu_y, s2, sxy)
    __shared__ float  s_red[4];         // ~25.6 KB total -> 6 blocks/CU

    const int tid = threadIdx.x;
    const int plane = blockIdx.z;              // b*3 + c
    const int tx0 = blockIdx.x * TW;
    const int ty0 = blockIdx.y * TH;
    const int pbase = plane * (IMG * IMG);
    const int cbase = (plane / 3) * (IMG * IMG);

    // Gaussian symmetric: g[k] == g[10-k] bitwise. 6 distinct packed weights.
    constexpr int WI[11] = {0,1,2,3,4,5,4,3,2,1,0};
    v2f w2[6];
    #pragma unroll
    for (int i = 0; i < 6; i++) w2[i] = (v2f){W.g[i], W.g[i]};

    // ---- Phase 1: horizontal pass, direct from global ----
    // 50 rows x 4 col-groups = 200 strips, one per thread, ONE round.
    // Strip = 8 output cols; reads 6 aligned float4s per array covering cols
    // [cs-8, cs+16); elements 3..20 are the 18 taps. 16B-aligned reads are
    // fully in- or out-of-bounds -> exact zero padding.
    if (tid < HR * 4) {
        const int r = tid >> 2;
        const int cs = (tid & 3) * 8;
        const int gy = ty0 - 5 + r;
        const float* xrow = x + pbase + gy * IMG;
        const float* yrow = y + pbase + gy * IMG;
        const int c0 = tx0 + cs - 8;

        // Per-strip fast-path guard (R6-verified): row in-bounds AND col
        // window [c0, c0+24) within [0,512).
        const bool fast = ((unsigned)gy < IMG) & ((unsigned)c0 <= (unsigned)(IMG - 24));

        float4 fx[6], fy[6];
        if (fast) {
            #pragma unroll
            for (int q = 0; q < 6; q++) {
                fx[q] = *(const float4*)(xrow + c0 + 4 * q);
                fy[q] = *(const float4*)(yrow + c0 + 4 * q);
            }
        } else {
            const bool rowok = ((unsigned)gy < IMG);
            #pragma unroll
            for (int q = 0; q < 6; q++) {
                int col = c0 + 4 * q;
                fx[q] = make_float4(0.f, 0.f, 0.f, 0.f);
                fy[q] = make_float4(0.f, 0.f, 0.f, 0.f);
                if (rowok && (unsigned)col <= (unsigned)(IMG - 4)) {
                    fx[q] = *(const float4*)(xrow + col);
                    fy[q] = *(const float4*)(yrow + col);
                }
            }
        }
        float vxa[24], vya[24];
        #pragma unroll
        for (int q = 0; q < 6; q++) {
            vxa[4*q+0]=fx[q].x; vxa[4*q+1]=fx[q].y; vxa[4*q+2]=fx[q].z; vxa[4*q+3]=fx[q].w;
            vya[4*q+0]=fy[q].x; vya[4*q+1]=fy[q].y; vya[4*q+2]=fy[q].z; vya[4*q+3]=fy[q].w;
        }

        // Streaming tap-major conv over the two packed accumulators
        // (four-field: A=(x,y), B=(x^2+y^2, x*y)).
        v2f amu[8], a2[8];
        #pragma unroll
        for (int j = 0; j < 8; j++) { amu[j]=(v2f){0.f,0.f}; a2[j]=(v2f){0.f,0.f}; }
        #pragma unroll
        for (int k = 0; k < 18; k++) {
            float xv = vxa[k + 3], yv = vya[k + 3];
            v2f xy = (v2f){xv, yv};
            v2f p2 = xy * xy;                     // (x^2, y^2)
            v2f zw = (v2f){p2.x + p2.y, xv * yv}; // (x^2+y^2, x*y)
            const int jlo = (k - 10 > 0) ? (k - 10) : 0;
            const int jhi = (k < 7) ? k : 7;
            #pragma unroll
            for (int j = jlo; j <= jhi; j++) {
                v2f w = w2[WI[k - j]];
                amu[j] = pk_fma(xy, w, amu[j]);
                a2[j]  = pk_fma(zw, w, a2[j]);
            }
        }
        const int quad = cs & 24;
        const int base0 = cs + 2 * (cs >> 3) + 5 * r;
        #pragma unroll
        for (int j = 0; j < 8; j++) {
            int pc = quad | ((base0 + j) & 7);
            s_h[r * TW + pc] = make_float4(amu[j].x, amu[j].y, a2[j].x, a2[j].y);
        }
    }

    // Prefetch conf (consumed in epilogue) before the barrier.
    // Tail block (by=12) rows >= 512 get cf=0 and contribute exactly 0
    // (den >= C1*C2 > 0, finite loss) -- no other guard needed.
    const int c  = tid & 31;
    const int r0 = (tid >> 5) * 5;            // 8 groups x 5 rows = 40 rows
    float cf[5];
    #pragma unroll
    for (int j = 0; j < 5; j++) {
        int gy = ty0 + r0 + j;
        cf[j] = (gy < IMG) ? conf[cbase + gy * IMG + tx0 + c] : 0.f;
    }
    __syncthreads();

    // ---- Phase 2: vertical pass, 5 vertically-adjacent outputs per thread ----
    // Swizzled col index pc(t) has period 8 in t (5*8 == 0 mod 8): precompute
    // the 8 base indices; t*TW folds into the ds_read offset immediate
    // (max 14*512 = 7168 B < 64 KiB) -> zero per-iteration address VALU.
    v2f amu[5], a2[5];
    #pragma unroll
    for (int j = 0; j < 5; j++) { amu[j]=(v2f){0.f,0.f}; a2[j]=(v2f){0.f,0.f}; }

    const int cquad = c & 24;
    const int cb0 = c + 2 * (c >> 3) + 5 * r0;
    int bidx[8];
    #pragma unroll
    for (int p = 0; p < 8; p++) {
        bidx[p] = r0 * TW + (cquad | ((cb0 + 5 * p) & 7));
    }
    #pragma unroll
    for (int t = 0; t < 15; t++) {
        float4 h4 = s_h[bidx[t & 7] + t * TW];
        v2f hmu = (v2f){h4.x, h4.y};
        v2f h2  = (v2f){h4.z, h4.w};
        #pragma unroll
        for (int j = 0; j < 5; j++) {
            int k = t - j;                    // constant post-unroll
            if (k >= 0 && k <= 10) {
                v2f w = w2[WI[k]];
                amu[j] = pk_fma(hmu, w, amu[j]);
                a2[j]  = pk_fma(h2, w, a2[j]);
            }
        }
    }

    // ---- Epilogue: SSIM + conf weighting + accumulate ----
    float lsum = 0.f;
    #pragma unroll
    for (int j = 0; j < 5; j++) {
        float mu_x = amu[j].x, mu_y = amu[j].y;
        v2f prod = amu[j] * amu[j];           // (mu_x^2, mu_y^2), packed
        float mu_xy = mu_x * mu_y;
        float musq  = prod.x + prod.y;        // mu_x^2 + mu_y^2
        float sigsum = a2[j].x - musq;        // sigma_x^2 + sigma_y^2
        float sigxy  = a2[j].y - mu_xy;
        float num = fmaf(2.f, mu_xy, SSIM_C1) * fmaf(2.f, sigxy, SSIM_C2);
        float den = (musq + SSIM_C1) * (sigsum + SSIM_C2);
        float ssim = num * __builtin_amdgcn_rcpf(den);   // den >= C1*C2 > 0
        float loss = fminf(fmaxf(1.f - ssim, 0.f), 1.f);
        lsum = fmaf(loss, cf[j], lsum);
    }

    // ---- Block reduction ----
    #pragma unroll
    for (int off = 32; off; off >>= 1) lsum += __shfl_down(lsum, off, 64);
    if ((tid & 63) == 0) s_red[tid >> 6] = lsum;
    __syncthreads();
    if (tid == 0) {
        float t = s_red[0] + s_red[1] + s_red[2] + s_red[3];
        if (use_ws) {
            partials[blockIdx.x + gridDim.x * (blockIdx.y + gridDim.y * blockIdx.z)] = t;
        } else {
            atomicAdd(out, t * scale);
        }
    }
}

// Single-block reduce: writes out[0] directly (no memset, no atomics).
__global__ void reduce_kernel(const float* __restrict__ partials, int n,
                              float* __restrict__ out, float scale) {
    __shared__ float s_red[16];
    float s = 0.f;
    const float4* p4 = (const float4*)partials;
    const int n4 = n >> 2;
    for (int i = threadIdx.x; i < n4; i += 1024) {
        float4 v = p4[i];
        s += (v.x + v.y) + (v.z + v.w);
    }
    for (int i = (n4 << 2) + threadIdx.x; i < n; i += 1024) s += partials[i];
    #pragma unroll
    for (int off = 32; off; off >>= 1) s += __shfl_down(s, off, 64);
    if ((threadIdx.x & 63) == 0) s_red[threadIdx.x >> 6] = s;
    __syncthreads();
    if (threadIdx.x == 0) {
        float t = 0.f;
        #pragma unroll
        for (int i = 0; i < 16; i++) t += s_red[i];
        out[0] = t * scale;
    }
}

extern "C" void kernel_launch(void* const* d_in, const int* in_sizes, int n_in,
                              void* d_out, int out_size, void* d_ws, size_t ws_size,
                              hipStream_t stream) {
    const float* x    = (const float*)d_in[0];
    const float* y    = (const float*)d_in[1];
    const float* conf = (const float*)d_in[2];
    float* out = (float*)d_out;
    float* partials = (float*)d_ws;

    // Gaussian window, computed like the reference: float64 exp + normalize, cast f32
    GaussWin W;
    {
        double gd[11], s = 0.0;
        for (int i = 0; i < 11; i++) { gd[i] = exp(-((i - 5) * (i - 5)) / 4.5); s += gd[i]; }
        for (int i = 0; i < 11; i++) W.g[i] = (float)(gd[i] / s);
    }

    const int B = 16, C = 3;
    const float scale = 1.0f / (float)(B * C * IMG * IMG);
    const int gy_blocks = (IMG + TH - 1) / TH;              // 13 (last block masked)
    dim3 grid(IMG / TW, gy_blocks, B * C);                  // 16 x 13 x 48 = 9984 blocks
    const int nblocks = (IMG / TW) * gy_blocks * B * C;
    const int use_ws = (ws_size >= (size_t)nblocks * sizeof(float)) ? 1 : 0;

    if (!use_ws) {
        // fallback: atomic accumulation into d_out (poisoned before each call)
        hipMemsetAsync(d_out, 0, sizeof(float), stream);
    }
    ssim_tile_kernel<<<grid, NT, 0, stream>>>(x, y, conf, partials, out, use_ws, scale, W);
    if (use_ws) {
        reduce_kernel<<<1, 1024, 0, stream>>>(partials, nblocks, out, scale);
    }
}

// Round 11
// 152.321 us; speedup vs baseline: 1.1022x; 1.0106x over previous
//
#include <hip/hip_runtime.h>
#include <cmath>

#define TW 32
#define TH 32
#define HR (TH + 10)     // 42 rows of h-pass results
#define NT 256
#define IMG 512
#define SSIM_C1 1e-4f
#define SSIM_C2 9e-4f

struct GaussWin { float g[11]; };

typedef float v2f __attribute__((ext_vector_type(2)));

// Native packed fp32: clang/LLVM selects v_pk_fma_f32 for <2 x float> on
// gfx90a+ (HasPackedFP32Ops).
__device__ __forceinline__ v2f pk_fma(v2f a, v2f b, v2f c) {
    return __builtin_elementwise_fma(a, b, c);
}

// R11 = R2 (the measured session optimum: TH=32, 7 blocks/CU, 57.3 us,
// busy 69%) + the two micro-trims proven in later rounds:
//  - phase-2 period-8 bidx addressing (R8/R10): swizzled col pc(t) has
//    period 8 in t (5*8 == 0 mod 8); 8 precomputed bases + t*TW folded
//    into the ds_read offset immediate -> zero per-iteration address VALU
//    (saves ~42 insts/thread of ~215 in phase 2).
//  - per-strip fast-path guard (R6/R10): replaces the block-level interior
//    flag; edge blocks take the fast path for in-bounds strips.
// Frontier fully mapped (TH=32/40/48/64 -> 57.3/61.5/59.0/62+): taller
// tiles cut work but lose more to idle; fatter/fewer-block structures
// (R3/R5/R6/R7/R9) all starve latency cover. Warm-L3 dispatches run at
// identical dur (R10) -> purely VALU-issue/latency bound, HBM irrelevant.
__launch_bounds__(NT, 4)
__global__ void ssim_tile_kernel(const float* __restrict__ x,
                                 const float* __restrict__ y,
                                 const float* __restrict__ conf,
                                 float* __restrict__ partials,
                                 float* __restrict__ out,
                                 int use_ws, float scale,
                                 GaussWin W) {
    __shared__ float4 s_h[HR * TW];     // 21504 B  (mu_x, mu_y, s2, sxy)
    __shared__ float  s_red[4];         // ~21.6 KB total -> 7 blocks/CU

    const int tid = threadIdx.x;
    const int plane = blockIdx.z;              // b*3 + c
    const int tx0 = blockIdx.x * TW;
    const int ty0 = blockIdx.y * TH;
    const int pbase = plane * (IMG * IMG);
    const int cbase = (plane / 3) * (IMG * IMG);

    // Gaussian symmetric: g[k] == g[10-k] bitwise. 6 distinct packed weights.
    constexpr int WI[11] = {0,1,2,3,4,5,4,3,2,1,0};
    v2f w2[6];
    #pragma unroll
    for (int i = 0; i < 6; i++) w2[i] = (v2f){W.g[i], W.g[i]};

    // ---- Phase 1: horizontal pass, direct from global ----
    // 42 rows x 4 col-groups = 168 strips, one per thread, one round.
    // Strip = 8 output cols; reads 6 aligned float4s per array covering cols
    // [cs-8, cs+16); elements 3..20 are the 18 taps. 16B-aligned reads are
    // fully in- or out-of-bounds -> exact zero padding.
    if (tid < HR * 4) {
        const int r = tid >> 2;
        const int cs = (tid & 3) * 8;
        const int gy = ty0 - 5 + r;
        const float* xrow = x + pbase + gy * IMG;
        const float* yrow = y + pbase + gy * IMG;
        const int c0 = tx0 + cs - 8;

        // Per-strip fast-path guard (R6/R10-verified): row in-bounds AND
        // col window [c0, c0+24) within [0,512).
        const bool fast = ((unsigned)gy < IMG) & ((unsigned)c0 <= (unsigned)(IMG - 24));

        float4 fx[6], fy[6];
        if (fast) {
            #pragma unroll
            for (int q = 0; q < 6; q++) {
                fx[q] = *(const float4*)(xrow + c0 + 4 * q);
                fy[q] = *(const float4*)(yrow + c0 + 4 * q);
            }
        } else {
            const bool rowok = ((unsigned)gy < IMG);
            #pragma unroll
            for (int q = 0; q < 6; q++) {
                int col = c0 + 4 * q;
                fx[q] = make_float4(0.f, 0.f, 0.f, 0.f);
                fy[q] = make_float4(0.f, 0.f, 0.f, 0.f);
                if (rowok && (unsigned)col <= (unsigned)(IMG - 4)) {
                    fx[q] = *(const float4*)(xrow + col);
                    fy[q] = *(const float4*)(yrow + col);
                }
            }
        }
        float vxa[24], vya[24];
        #pragma unroll
        for (int q = 0; q < 6; q++) {
            vxa[4*q+0]=fx[q].x; vxa[4*q+1]=fx[q].y; vxa[4*q+2]=fx[q].z; vxa[4*q+3]=fx[q].w;
            vya[4*q+0]=fy[q].x; vya[4*q+1]=fy[q].y; vya[4*q+2]=fy[q].z; vya[4*q+3]=fy[q].w;
        }

        // Streaming tap-major conv over the two packed accumulators
        // (four-field: A=(x,y), B=(x^2+y^2, x*y)).
        v2f amu[8], a2[8];
        #pragma unroll
        for (int j = 0; j < 8; j++) { amu[j]=(v2f){0.f,0.f}; a2[j]=(v2f){0.f,0.f}; }
        #pragma unroll
        for (int k = 0; k < 18; k++) {
            float xv = vxa[k + 3], yv = vya[k + 3];
            v2f xy = (v2f){xv, yv};
            v2f p2 = xy * xy;                     // (x^2, y^2)
            v2f zw = (v2f){p2.x + p2.y, xv * yv}; // (x^2+y^2, x*y)
            const int jlo = (k - 10 > 0) ? (k - 10) : 0;
            const int jhi = (k < 7) ? k : 7;
            #pragma unroll
            for (int j = jlo; j <= jhi; j++) {
                v2f w = w2[WI[k - j]];
                amu[j] = pk_fma(xy, w, amu[j]);
                a2[j]  = pk_fma(zw, w, a2[j]);
            }
        }
        const int quad = cs & 24;
        const int base0 = cs + 2 * (cs >> 3) + 5 * r;
        #pragma unroll
        for (int j = 0; j < 8; j++) {
            int pc = quad | ((base0 + j) & 7);
            s_h[r * TW + pc] = make_float4(amu[j].x, amu[j].y, a2[j].x, a2[j].y);
        }
    }

    // Prefetch conf (consumed in epilogue) before the barrier.
    // 16x16 grid covers 512 rows exactly -> no bounds guard needed.
    const int c  = tid & 31;
    const int r0 = (tid >> 5) * 4;            // 8 groups x 4 rows = 32 rows
    float cf[4];
    #pragma unroll
    for (int j = 0; j < 4; j++) {
        cf[j] = conf[cbase + (ty0 + r0 + j) * IMG + tx0 + c];
    }
    __syncthreads();

    // ---- Phase 2: vertical pass, 4 vertically-adjacent outputs per thread ----
    // Period-8 bidx addressing (R8/R10): 8 precomputed swizzle bases;
    // t*TW (16 B/float4) folds into the ds_read offset immediate
    // (max 13*512 = 6656 B < 64 KiB) -> zero per-iteration address VALU.
    v2f amu[4], a2[4];
    #pragma unroll
    for (int j = 0; j < 4; j++) { amu[j]=(v2f){0.f,0.f}; a2[j]=(v2f){0.f,0.f}; }

    const int cquad = c & 24;
    const int cb0 = c + 2 * (c >> 3) + 5 * r0;
    int bidx[8];
    #pragma unroll
    for (int p = 0; p < 8; p++) {
        bidx[p] = r0 * TW + (cquad | ((cb0 + 5 * p) & 7));
    }
    #pragma unroll
    for (int t = 0; t < 14; t++) {
        float4 h4 = s_h[bidx[t & 7] + t * TW];
        v2f hmu = (v2f){h4.x, h4.y};
        v2f h2  = (v2f){h4.z, h4.w};
        #pragma unroll
        for (int j = 0; j < 4; j++) {
            int k = t - j;                    // constant post-unroll
            if (k >= 0 && k <= 10) {
                v2f w = w2[WI[k]];
                amu[j] = pk_fma(hmu, w, amu[j]);
                a2[j]  = pk_fma(h2, w, a2[j]);
            }
        }
    }

    // ---- Epilogue: SSIM + conf weighting + accumulate ----
    float lsum = 0.f;
    #pragma unroll
    for (int j = 0; j < 4; j++) {
        float mu_x = amu[j].x, mu_y = amu[j].y;
        v2f prod = amu[j] * amu[j];           // (mu_x^2, mu_y^2), packed
        float mu_xy = mu_x * mu_y;
        float musq  = prod.x + prod.y;        // mu_x^2 + mu_y^2
        float sigsum = a2[j].x - musq;        // sigma_x^2 + sigma_y^2
        float sigxy  = a2[j].y - mu_xy;
        float num = fmaf(2.f, mu_xy, SSIM_C1) * fmaf(2.f, sigxy, SSIM_C2);
        float den = (musq + SSIM_C1) * (sigsum + SSIM_C2);
        float ssim = num * __builtin_amdgcn_rcpf(den);   // den >= C1*C2 > 0
        float loss = fminf(fmaxf(1.f - ssim, 0.f), 1.f);
        lsum = fmaf(loss, cf[j], lsum);
    }

    // ---- Block reduction ----
    #pragma unroll
    for (int off = 32; off; off >>= 1) lsum += __shfl_down(lsum, off, 64);
    if ((tid & 63) == 0) s_red[tid >> 6] = lsum;
    __syncthreads();
    if (tid == 0) {
        float t = s_red[0] + s_red[1] + s_red[2] + s_red[3];
        if (use_ws) {
            partials[blockIdx.x + gridDim.x * (blockIdx.y + gridDim.y * blockIdx.z)] = t;
        } else {
            atomicAdd(out, t * scale);
        }
    }
}

// Single-block reduce: writes out[0] directly (no memset, no atomics).
__global__ void reduce_kernel(const float* __restrict__ partials, int n,
                              float* __restrict__ out, float scale) {
    __shared__ float s_red[16];
    float s = 0.f;
    const float4* p4 = (const float4*)partials;
    const int n4 = n >> 2;
    for (int i = threadIdx.x; i < n4; i += 1024) {
        float4 v = p4[i];
        s += (v.x + v.y) + (v.z + v.w);
    }
    for (int i = (n4 << 2) + threadIdx.x; i < n; i += 1024) s += partials[i];
    #pragma unroll
    for (int off = 32; off; off >>= 1) s += __shfl_down(s, off, 64);
    if ((threadIdx.x & 63) == 0) s_red[threadIdx.x >> 6] = s;
    __syncthreads();
    if (threadIdx.x == 0) {
        float t = 0.f;
        #pragma unroll
        for (int i = 0; i < 16; i++) t += s_red[i];
        out[0] = t * scale;
    }
}

extern "C" void kernel_launch(void* const* d_in, const int* in_sizes, int n_in,
                              void* d_out, int out_size, void* d_ws, size_t ws_size,
                              hipStream_t stream) {
    const float* x    = (const float*)d_in[0];
    const float* y    = (const float*)d_in[1];
    const float* conf = (const float*)d_in[2];
    float* out = (float*)d_out;
    float* partials = (float*)d_ws;

    // Gaussian window, computed like the reference: float64 exp + normalize, cast f32
    GaussWin W;
    {
        double gd[11], s = 0.0;
        for (int i = 0; i < 11; i++) { gd[i] = exp(-((i - 5) * (i - 5)) / 4.5); s += gd[i]; }
        for (int i = 0; i < 11; i++) W.g[i] = (float)(gd[i] / s);
    }

    const int B = 16, C = 3;
    const float scale = 1.0f / (float)(B * C * IMG * IMG);
    dim3 grid(IMG / TW, IMG / TH, B * C);                   // 16 x 16 x 48 = 12288 blocks
    const int nblocks = (IMG / TW) * (IMG / TH) * B * C;
    const int use_ws = (ws_size >= (size_t)nblocks * sizeof(float)) ? 1 : 0;

    if (!use_ws) {
        // fallback: atomic accumulation into d_out (poisoned before each call)
        hipMemsetAsync(d_out, 0, sizeof(float), stream);
    }
    ssim_tile_kernel<<<grid, NT, 0, stream>>>(x, y, conf, partials, out, use_ws, scale, W);
    if (use_ws) {
        reduce_kernel<<<1, 1024, 0, stream>>>(partials, nblocks, out, scale);
    }
}